// Round 6
// baseline (99.139 us; speedup 1.0000x reference)
//
#include <hip/hip_runtime.h>
#include <cstdint>

#define BB 4
#define RR 512
#define CC 80
#define KK 100
#define GSPLIT 5
#define NMS_TH 0.3f
#define SCORE_TH 0.1f
#define DWH_CLIP 4.135166556742356f

typedef unsigned short u16;
typedef unsigned int u32;
typedef unsigned long long u64;

__device__ __forceinline__ u32 f32_sortable(float f) {
  u32 u = __float_as_uint(f);
  u32 mask = (u32)((int)u >> 31) | 0x80000000u;
  return u ^ mask;
}
__device__ __forceinline__ float sortable_to_f32(u32 s) {
  u32 u = (s & 0x80000000u) ? (s ^ 0x80000000u) : ~s;
  return __uint_as_float(u);
}
__device__ __forceinline__ float rdlanef(float v, int l) {
  return __int_as_float(__builtin_amdgcn_readlane(__float_as_int(v), l));
}

// Kernel 1: grid = B*C*GSPLIT blocks of 512. Each block sorts+decodes its
// (b,c) problem (redundant across the GSPLIT group — cheap), then each of its
// 8 waves computes one 64x64 IoU tile of the upper-triangular suppression
// bitmask, written to global. Group g==0 also stages sorted boxes+scores.
__global__ __launch_bounds__(512) void nms_tiles(
    const float* __restrict__ rois,     // [B,R,4]
    const float* __restrict__ scores,   // [B*R, C+1]
    const float* __restrict__ deltas,   // [B*R, (C+1)*4]
    const int*   __restrict__ im_hw,    // [B,2]
    u64*   __restrict__ cmg,            // [B*C, 36, 64]
    float4* __restrict__ box_g,         // [B*C, R]
    float*  __restrict__ sco_g)         // [B*C, R]
{
#pragma clang fp contract(off)
  const int blk = blockIdx.x;
  const int bc = blk / GSPLIT, g = blk % GSPLIT;
  const int b = bc / CC, c = bc % CC;
  const int tid = threadIdx.x;
  const int lane = tid & 63, wv = tid >> 6;

  __shared__ u64    keyarr[RR];         // 4 KB
  __shared__ float4 box_s[RR];          // 8 KB

  const float fh = (float)im_hw[b * 2 + 0] - 1.0f;
  const float fw = (float)im_hw[b * 2 + 1] - 1.0f;

  // ---- sort keys (hybrid bitonic, 512 elems / 512 thr) ----
  {
    const float sc = scores[(b * RR + tid) * (CC + 1) + (c + 1)];
    u64 v = ((u64)(~f32_sortable(sc)) << 32) | (u32)tid;  // score desc, idx asc
    const u32 t = (u32)tid;
    for (u32 kk = 2; kk <= RR; kk <<= 1) {
      for (u32 j = kk >> 1; j > 0; j >>= 1) {
        u64 p;
        if (j >= 64) {
          keyarr[t] = v;
          __syncthreads();
          p = keyarr[t ^ j];
          __syncthreads();
        } else {
          p = __shfl_xor(v, (int)j);
        }
        bool up = ((t & kk) == 0);
        bool lower = ((t & j) == 0);
        bool takemin = (up == lower);
        bool pless = (p < v);
        v = (takemin == pless) ? p : v;
      }
    }
    keyarr[t] = v;
  }
  __syncthreads();

  // ---- decode into sorted order (1 elem/thread) ----
  {
    const u64 kv = keyarr[tid];
    const int r = (int)(kv & 0xFFFFFFFFull);
    const float sc = sortable_to_f32(~(u32)(kv >> 32));   // bit-exact original
    const float4 roi = *(const float4*)&rois[(b * RR + r) * 4];
    const int base = (b * RR + r) * (CC + 1) + (c + 1);
    const float4 d = *(const float4*)&deltas[base * 4];

    float w  = roi.z - roi.x;
    float h  = roi.w - roi.y;
    float cx = roi.x + 0.5f * w;
    float cy = roi.y + 0.5f * h;
    float dw = fminf(d.z, DWH_CLIP);
    float dh = fminf(d.w, DWH_CLIP);
    float pcx = d.x * w + cx;
    float pcy = d.y * h + cy;
    float pw = w * expf(dw);
    float ph = h * expf(dh);
    float hx = 0.5f * pw, hy = 0.5f * ph;
    float x1 = fminf(fmaxf(pcx - hx, 0.0f), fw);
    float y1 = fminf(fmaxf(pcy - hy, 0.0f), fh);
    float x2 = fminf(fmaxf(pcx + hx, 0.0f), fw);
    float y2 = fminf(fmaxf(pcy + hy, 0.0f), fh);

    float4 bx = make_float4(x1, y1, x2, y2);
    box_s[tid] = bx;
    if (g == 0) { box_g[bc * RR + tid] = bx; sco_g[bc * RR + tid] = sc; }
  }
  __syncthreads();

  // ---- one IoU tile per wave. lane = row; iterate 64 columns; column box
  // broadcast via readlane; colmask word produced directly by ballot; lane j
  // captures the ballot for column j via predicated select (ballot result is
  // wave-uniform). Certain-test: q > TH <=> inter*(1+TH)/TH > ai+aj+1e-9
  // (exact reals); conservative band +-2e-6 (>> all rounding error ~3e-7),
  // exact IEEE-divide fallback for band cases (essentially never taken).
  const int t0 = g * 8 + wv;
  if (t0 < 36) {
    int jb = 0, tt = t0;
    while (tt >= jb + 1) { tt -= (jb + 1); ++jb; }
    const int w = tt;                      // row chunk (w <= jb)
    const float4 rb4 = box_s[w * 64 + lane];
    const float ra = (rb4.z - rb4.x) * (rb4.w - rb4.y);
    const float4 cb4 = box_s[jb * 64 + lane];
    const float ca = (cb4.z - cb4.x) * (cb4.w - cb4.y);
    const float cS = ca + 1e-9f;
    u64 word = 0;
    #pragma unroll 8
    for (int j = 0; j < 64; ++j) {
      const float bx1 = rdlanef(cb4.x, j);
      const float by1 = rdlanef(cb4.y, j);
      const float bx2 = rdlanef(cb4.z, j);
      const float by2 = rdlanef(cb4.w, j);
      const float sS  = rdlanef(cS, j);
      float iw = fminf(rb4.z, bx2) - fmaxf(rb4.x, bx1);
      float ih = fminf(rb4.w, by2) - fmaxf(rb4.y, by1);
      iw = fmaxf(iw, 0.0f);
      ih = fmaxf(ih, 0.0f);
      const float inter = iw * ih;
      const float S = ra + sS;
      u64 yesm = __ballot(inter * 4.3333247f > S);      // 13/3*(1-2e-6)
      const u64 nom = __ballot(inter * 4.3333420f < S); // 13/3*(1+2e-6)
      const u64 uncm = ~(yesm | nom);
      if (uncm) {                                       // ~never taken
        const float aj = rdlanef(ca, j);
        const float denom = ((ra + aj) - inter) + 1e-9f; // exact ref order
        const float q = inter / denom;
        const u64 pem = __ballot(q > NMS_TH);
        yesm = (yesm & ~uncm) | (pem & uncm);
      }
      word = (lane == j) ? yesm : word;                 // lane j keeps col j
    }
    if (jb == w) word &= (1ull << lane) - 1ull;         // diagonal: row < col
    cmg[((size_t)(bc * 36 + t0)) * 64 + lane] = word;
  }
}

// Kernel 2: one block of 512 per (b,c). Load bitmask tiles + scores to LDS,
// wave 0 runs the greedy scan, emit first <=100 kept candidates.
__global__ __launch_bounds__(512) void nms_scan(
    const u64* __restrict__ cmg,
    const float4* __restrict__ box_g,
    const float* __restrict__ sco_g,
    u64*   __restrict__ cand_key,        // [B*C, K]
    float4* __restrict__ cand_box)       // [B*C, K]
{
  const int bc = blockIdx.x;
  const int c = bc % CC;
  const int tid = threadIdx.x;
  const int lane = tid & 63, wv = tid >> 6;

  __shared__ u64   cm[36 * 64];          // 18 KB
  __shared__ float sco_s[RR];
  __shared__ int   klist[KK];
  __shared__ int   nkept_s;

  for (int e = tid; e < 36 * 64; e += 512) cm[e] = cmg[(size_t)bc * (36 * 64) + e];
  for (int e = tid; e < RR; e += 512) sco_s[e] = sco_g[bc * RR + e];
  __syncthreads();

  if (wv == 0) {
    u64 kall[8];
    int nk = 0;
    #pragma unroll
    for (int w = 0; w < 8; ++w) {
      const int tri = w * (w + 1) / 2;
      const u64 mycol = cm[(tri + w) * 64 + lane];
      u64 pres = 0;
      #pragma unroll
      for (int w2 = 0; w2 < w; ++w2) pres |= cm[(tri + w2) * 64 + lane] & kall[w2];
      u64 sup = __ballot(pres != 0);
      const u64 ok = __ballot(sco_s[w * 64 + lane] > SCORE_TH);
      u64 keepm = 0;
      u64 todo = ok & ~sup;
      while (todo) {
        const int i = __ffsll((long long)todo) - 1;
        keepm |= 1ull << i;
        sup |= __ballot((mycol >> i) & 1ull);
        todo &= ~(sup | (1ull << i));
      }
      kall[w] = keepm;
      if ((keepm >> lane) & 1ull) {
        int rank = nk + __popcll(keepm & ((1ull << lane) - 1ull));
        if (rank < KK) klist[rank] = w * 64 + lane;
      }
      nk += __popcll(keepm);
    }
    if (lane == 0) nkept_s = nk;
  }
  __syncthreads();

  const int nk = min(nkept_s, KK);
  if (tid < KK) {
    const int k = tid;
    u64 kv; float4 bx;
    if (k < nk) {
      const int i = klist[k];
      kv = ((u64)(~f32_sortable(sco_s[i])) << 32) | ((u64)(u32)c << 16) | (u32)k;
      bx = box_g[bc * RR + i];
    } else {
      kv = ((u64)(~f32_sortable(-1e9f)) << 32) | ((u64)(u32)c << 16) | (u32)k;
      bx = make_float4(0.f, 0.f, 0.f, 0.f);
    }
    cand_key[bc * KK + k] = kv;
    cand_box[bc * KK + k] = bx;
  }
}

// Kernel 3: one block per image. Radix-select rank-99 key T over 8000 unique
// keys (wave-sliced histograms, wave-aggregated compaction), gather the
// exactly-100 keys <= T, hybrid-sort 128, write [K,6].
__global__ __launch_bounds__(1024) void topk_select(
    const u64* __restrict__ cand_key,    // [B, C*K]
    const float4* __restrict__ cand_box, // [B*C, K]
    float* __restrict__ out)             // [B, K, 6]
{
  const int b = blockIdx.x;
  const int tid = threadIdx.x;
  const int lane = tid & 63, wv = tid >> 6;
  const int N = CC * KK;                 // 8000
  const u64* __restrict__ keys_g = cand_key + (size_t)b * N;

  __shared__ u16 candA[CC * KK];         // 16 KB
  __shared__ u16 candB[CC * KK];         // 16 KB
  __shared__ u32 whist[16][256];         // 16 KB
  __shared__ u32 bins[256];
  __shared__ u64 smallkeys[128];
  __shared__ int ncand_s, rank_s, q_s;
  __shared__ u32 cnt_s;

  if (tid == 0) { ncand_s = N; rank_s = KK - 1; }

  u16* cur = candA;
  u16* oth = candB;
  bool first = true;
  int d = 7;
  for (;;) {
    for (int t = tid; t < 16 * 256; t += 1024) ((u32*)whist)[t] = 0;
    __syncthreads();
    const int nc = first ? N : ncand_s;
    const int sh = d * 8;
    for (int t0 = 0; t0 < nc; t0 += 1024) {
      const int t = t0 + tid;
      if (t < nc) {
        const int idx = first ? t : (int)cur[t];
        u32 dig = (u32)((keys_g[idx] >> sh) & 0xFF);
        atomicAdd(&whist[wv][dig], 1u);
      }
    }
    __syncthreads();
    if (tid < 256) {
      u32 s = 0;
      #pragma unroll
      for (int w = 0; w < 16; ++w) s += whist[w][tid];
      bins[tid] = s;
    }
    __syncthreads();
    if (wv == 0) {
      u32 c0 = bins[lane * 4 + 0], c1 = bins[lane * 4 + 1];
      u32 c2 = bins[lane * 4 + 2], c3 = bins[lane * 4 + 3];
      u32 lsum = c0 + c1 + c2 + c3;
      u32 incl = lsum;
      #pragma unroll
      for (int off = 1; off < 64; off <<= 1) {
        u32 v = __shfl_up(incl, off);
        if (lane >= off) incl += v;
      }
      u32 excl = incl - lsum;
      int rk = rank_s;
      u32 s0 = excl, s1 = excl + c0, s2 = s1 + c1, s3 = s2 + c2;
      int q = -1; u32 nr = 0;
      if (rk >= (int)s0 && rk < (int)(s0 + c0)) { q = lane * 4 + 0; nr = rk - s0; }
      else if (rk >= (int)s1 && rk < (int)(s1 + c1)) { q = lane * 4 + 1; nr = rk - s1; }
      else if (rk >= (int)s2 && rk < (int)(s2 + c2)) { q = lane * 4 + 2; nr = rk - s2; }
      else if (rk >= (int)s3 && rk < (int)(s3 + c3)) { q = lane * 4 + 3; nr = rk - s3; }
      if (q >= 0) { q_s = q; rank_s = (int)nr; }
    }
    if (tid == 0) cnt_s = 0;
    __syncthreads();
    const int q = q_s;
    for (int t0 = 0; t0 < nc; t0 += 1024) {
      const int t = t0 + tid;
      int idx = 0; bool m = false;
      if (t < nc) {
        idx = first ? t : (int)cur[t];
        m = ((int)((keys_g[idx] >> sh) & 0xFF) == q);
      }
      u64 bal = __ballot(m);
      u32 base = 0;
      if (lane == 0 && bal) base = atomicAdd(&cnt_s, (u32)__popcll(bal));
      base = __shfl(base, 0);
      if (m) oth[base + (u32)__popcll(bal & ((1ull << lane) - 1ull))] = (u16)idx;
    }
    __syncthreads();
    if (tid == 0) ncand_s = (int)cnt_s;
    { u16* tmp = cur; cur = oth; oth = tmp; }
    first = false;
    __syncthreads();
    if (ncand_s == 1 || d == 0) break;
    --d;
  }
  const u64 T = keys_g[cur[0]];

  if (tid == 0) cnt_s = 0;
  if (tid < 128) smallkeys[tid] = ~0ull;
  __syncthreads();
  for (int t0 = 0; t0 < N; t0 += 1024) {
    const int t = t0 + tid;
    u64 k = 0; bool m = false;
    if (t < N) { k = keys_g[t]; m = (k <= T); }
    u64 bal = __ballot(m);
    u32 base = 0;
    if (lane == 0 && bal) base = atomicAdd(&cnt_s, (u32)__popcll(bal));
    base = __shfl(base, 0);
    if (m) {
      u32 p = base + (u32)__popcll(bal & ((1ull << lane) - 1ull));
      if (p < 128) smallkeys[p] = k;
    }
  }
  __syncthreads();

  {
    u64 v = (tid < 128) ? smallkeys[tid] : ~0ull;
    const u32 t = (u32)tid;
    for (u32 kk = 2; kk <= 128; kk <<= 1) {
      for (u32 j = kk >> 1; j > 0; j >>= 1) {
        if (j >= 64) {
          if (tid < 128) smallkeys[t] = v;
          __syncthreads();
          u64 p = (tid < 128) ? smallkeys[t ^ j] : ~0ull;
          __syncthreads();
          if (tid < 128) {
            bool up = ((t & kk) == 0);
            bool lower = ((t & j) == 0);
            bool takemin = (up == lower);
            bool pless = (p < v);
            v = (takemin == pless) ? p : v;
          }
        } else if (tid < 128) {
          u64 p = __shfl_xor(v, (int)j);
          bool up = ((t & kk) == 0);
          bool lower = ((t & j) == 0);
          bool takemin = (up == lower);
          bool pless = (p < v);
          v = (takemin == pless) ? p : v;
        }
      }
    }
    if (tid < KK) {
      const u64 kv = v;
      const float s = sortable_to_f32(~(u32)(kv >> 32));
      float x1 = 0.f, y1 = 0.f, x2 = 0.f, y2 = 0.f, so = 0.f, cf = -1.0f;
      if (s > -5.0e8f) {
        int c = (int)((kv >> 16) & 0xFFFFull);
        int k = (int)(kv & 0xFFFFull);
        float4 bx = cand_box[((size_t)b * CC + c) * KK + k];
        x1 = bx.x; y1 = bx.y; x2 = bx.z; y2 = bx.w;
        so = s; cf = (float)c;
      }
      float* o = out + ((size_t)b * KK + tid) * 6;
      o[0] = x1; o[1] = y1; o[2] = x2; o[3] = y2; o[4] = so; o[5] = cf;
    }
  }
}

extern "C" void kernel_launch(void* const* d_in, const int* in_sizes, int n_in,
                              void* d_out, int out_size, void* d_ws, size_t ws_size,
                              hipStream_t stream) {
  (void)in_sizes; (void)n_in; (void)out_size; (void)ws_size;
  const float* rois   = (const float*)d_in[0];
  const float* scores = (const float*)d_in[1];
  const float* deltas = (const float*)d_in[2];
  const int*   im_hw  = (const int*)d_in[3];

  char* ws = (char*)d_ws;
  u64*    cmg      = (u64*)ws;                              // 320*36*64*8 = 5,898,240
  float4* box_g    = (float4*)(ws + 5898240);               // 320*512*16  = 2,621,440
  float*  sco_g    = (float*)(ws + 8519680);                // 320*512*4   =   655,360
  u64*    cand_key = (u64*)(ws + 9175040);                  // 4*80*100*8  =   256,000
  float4* cand_box = (float4*)(ws + 9431040);               // 4*80*100*16 =   512,000

  nms_tiles<<<BB * CC * GSPLIT, 512, 0, stream>>>(rois, scores, deltas, im_hw,
                                                  cmg, box_g, sco_g);
  nms_scan<<<BB * CC, 512, 0, stream>>>(cmg, box_g, sco_g, cand_key, cand_box);
  topk_select<<<BB, 1024, 0, stream>>>(cand_key, cand_box, (float*)d_out);
}

// Round 7
// 91.901 us; speedup vs baseline: 1.0788x; 1.0788x over previous
//
#include <hip/hip_runtime.h>
#include <cstdint>

#define BB 4
#define RR 512
#define CC 80
#define KK 100
#define NMS_TH 0.3f
#define SCORE_TH 0.1f
#define DWH_CLIP 4.135166556742356f

typedef unsigned short u16;
typedef unsigned int u32;
typedef unsigned long long u64;

__device__ __forceinline__ u32 f32_sortable(float f) {
  u32 u = __float_as_uint(f);
  u32 mask = (u32)((int)u >> 31) | 0x80000000u;
  return u ^ mask;
}
__device__ __forceinline__ float sortable_to_f32(u32 s) {
  u32 u = (s & 0x80000000u) ? (s ^ 0x80000000u) : ~s;
  return __uint_as_float(u);
}
__device__ __forceinline__ float rdlanef(float v, int l) {
  return __int_as_float(__builtin_amdgcn_readlane(__float_as_int(v), l));
}

// Kernel 1: one block of 512 per (b,c). Sort by score (desc, idx asc), decode
// boxes in sorted order, write sorted boxes + scores to workspace.
__global__ __launch_bounds__(512) void sort_decode(
    const float* __restrict__ rois,     // [B,R,4]
    const float* __restrict__ scores,   // [B*R, C+1]
    const float* __restrict__ deltas,   // [B*R, (C+1)*4]
    const int*   __restrict__ im_hw,    // [B,2]
    float4* __restrict__ box_g,         // [B*C, R]
    float*  __restrict__ sco_g)         // [B*C, R]
{
#pragma clang fp contract(off)
  const int bc = blockIdx.x;
  const int b = bc / CC, c = bc % CC;
  const int tid = threadIdx.x;

  __shared__ u64 keyarr[RR];

  const float fh = (float)im_hw[b * 2 + 0] - 1.0f;
  const float fw = (float)im_hw[b * 2 + 1] - 1.0f;

  // hybrid bitonic sort: shfl for j<64, LDS for j>=64
  {
    const float sc = scores[(b * RR + tid) * (CC + 1) + (c + 1)];
    u64 v = ((u64)(~f32_sortable(sc)) << 32) | (u32)tid;
    const u32 t = (u32)tid;
    for (u32 kk = 2; kk <= RR; kk <<= 1) {
      for (u32 j = kk >> 1; j > 0; j >>= 1) {
        u64 p;
        if (j >= 64) {
          keyarr[t] = v;
          __syncthreads();
          p = keyarr[t ^ j];
          __syncthreads();
        } else {
          p = __shfl_xor(v, (int)j);
        }
        bool up = ((t & kk) == 0);
        bool lower = ((t & j) == 0);
        bool takemin = (up == lower);
        bool pless = (p < v);
        v = (takemin == pless) ? p : v;
      }
    }
    keyarr[t] = v;
  }
  __syncthreads();

  {
    const u64 kv = keyarr[tid];
    const int r = (int)(kv & 0xFFFFFFFFull);
    const float sc = sortable_to_f32(~(u32)(kv >> 32));   // bit-exact original
    const float4 roi = *(const float4*)&rois[(b * RR + r) * 4];
    const int base = (b * RR + r) * (CC + 1) + (c + 1);
    const float4 d = *(const float4*)&deltas[base * 4];

    float w  = roi.z - roi.x;
    float h  = roi.w - roi.y;
    float cx = roi.x + 0.5f * w;
    float cy = roi.y + 0.5f * h;
    float dw = fminf(d.z, DWH_CLIP);
    float dh = fminf(d.w, DWH_CLIP);
    float pcx = d.x * w + cx;
    float pcy = d.y * h + cy;
    float pw = w * expf(dw);
    float ph = h * expf(dh);
    float hx = 0.5f * pw, hy = 0.5f * ph;
    float x1 = fminf(fmaxf(pcx - hx, 0.0f), fw);
    float y1 = fminf(fmaxf(pcy - hy, 0.0f), fh);
    float x2 = fminf(fmaxf(pcx + hx, 0.0f), fw);
    float y2 = fminf(fmaxf(pcy + hy, 0.0f), fh);

    box_g[bc * RR + tid] = make_float4(x1, y1, x2, y2);
    sco_g[bc * RR + tid] = sc;
  }
}

// Kernel 2: one WAVE per (b,c). Lazy greedy NMS: per 64-box chunk, suppress
// by previously-kept boxes (lane-distributed registers, readlane broadcast),
// then serial ballot scan within the chunk. Stops at 100 kept (exact: kept
// order == score order; suppression only flows forward). Certain-test:
// q > TH <=> inter*(1+TH)/TH > ai+aj+1e-9 (reals), band +-2e-6 >> rounding
// error ~3e-7, exact IEEE-divide fallback for band cases (validated R4/R6).
__global__ __launch_bounds__(64) void nms_lazy(
    const float4* __restrict__ box_g,   // [B*C, R] sorted
    const float*  __restrict__ sco_g,   // [B*C, R] sorted
    u64*   __restrict__ cand_key,       // [B*C, K]
    float4* __restrict__ cand_box)      // [B*C, K]
{
  const int bc = blockIdx.x;
  const int c = bc % CC;
  const int lane = threadIdx.x;

  __shared__ float4 kbox[KK];   // kept boxes (for output)
  __shared__ float  ksc[KK];    // kept scores (for output)

  // kept boxes for suppression, distributed: slot0 = kept[lane], slot1 = kept[64+lane]
  float r0x1 = 0.f, r0y1 = 0.f, r0x2 = 0.f, r0y2 = 0.f, r0a = 0.f;
  float r1x1 = 0.f, r1y1 = 0.f, r1x2 = 0.f, r1y2 = 0.f, r1a = 0.f;

  int nk = 0;
  for (int w = 0; w < 8 && nk < KK; ++w) {
    const float4 bx = box_g[bc * RR + w * 64 + lane];
    const float  sc = sco_g[bc * RR + w * 64 + lane];
    const float  ar = (bx.z - bx.x) * (bx.w - bx.y);
    const float  areps = ar + 1e-9f;
    const bool   dead0 = !(sc > SCORE_TH);

    bool sup = false;
    // suppression by previously-kept boxes
    for (int k = 0; k < nk; ++k) {
      float cx1, cy1, cx2, cy2, ca2;
      if (k < 64) {
        cx1 = rdlanef(r0x1, k); cy1 = rdlanef(r0y1, k);
        cx2 = rdlanef(r0x2, k); cy2 = rdlanef(r0y2, k);
        ca2 = rdlanef(r0a, k);
      } else {
        const int k2 = k - 64;
        cx1 = rdlanef(r1x1, k2); cy1 = rdlanef(r1y1, k2);
        cx2 = rdlanef(r1x2, k2); cy2 = rdlanef(r1y2, k2);
        ca2 = rdlanef(r1a, k2);
      }
      float iw = fminf(bx.z, cx2) - fmaxf(bx.x, cx1);
      float ih = fminf(bx.w, cy2) - fmaxf(bx.y, cy1);
      iw = fmaxf(iw, 0.0f);
      ih = fmaxf(ih, 0.0f);
      const float inter = iw * ih;
      const float S = ca2 + areps;
      bool yes = inter * 4.3333247f > S;       // 13/3*(1-2e-6)
      const bool no = inter * 4.3333420f < S;  // 13/3*(1+2e-6)
      if (__any(!(yes || no))) {               // ~never taken
        const float denom = ((ca2 + ar) - inter) + 1e-9f;  // exact ref order
        const bool pe = inter / denom > NMS_TH;
        yes = (yes || no) ? yes : pe;
      }
      sup = sup || yes;
      if (__all(sup || dead0)) break;          // chunk fully dead
    }

    // serial in-chunk scan
    u64 todo = __ballot(!dead0 && !sup);
    while (todo) {
      const int i = __ffsll((long long)todo) - 1;  // highest remaining score
      const float kx1 = rdlanef(bx.x, i), ky1 = rdlanef(bx.y, i);
      const float kx2 = rdlanef(bx.z, i), ky2 = rdlanef(bx.w, i);
      const float ka  = rdlanef(ar, i),   ks  = rdlanef(sc, i);
      if (lane == 0) { kbox[nk] = make_float4(kx1, ky1, kx2, ky2); ksc[nk] = ks; }
      if (nk < 64) {
        if (lane == nk) { r0x1 = kx1; r0y1 = ky1; r0x2 = kx2; r0y2 = ky2; r0a = ka; }
      } else {
        if (lane == nk - 64) { r1x1 = kx1; r1y1 = ky1; r1x2 = kx2; r1y2 = ky2; r1a = ka; }
      }
      ++nk;
      if (nk >= KK) break;
      float iw = fminf(bx.z, kx2) - fmaxf(bx.x, kx1);
      float ih = fminf(bx.w, ky2) - fmaxf(bx.y, ky1);
      iw = fmaxf(iw, 0.0f);
      ih = fmaxf(ih, 0.0f);
      const float inter = iw * ih;
      const float S = ka + areps;
      bool yes = inter * 4.3333247f > S;
      const bool no = inter * 4.3333420f < S;
      if (__any(!(yes || no))) {
        const float denom = ((ka + ar) - inter) + 1e-9f;
        const bool pe = inter / denom > NMS_TH;
        yes = (yes || no) ? yes : pe;
      }
      todo &= ~((2ull << i) - 1ull);           // clear bits <= i (i=63 -> 0)
      todo &= ~__ballot(yes);
    }
  }

  // emit (pads unique, score = -1e9 = reference NEG)
  for (int k = lane; k < KK; k += 64) {
    u64 kv; float4 obx;
    if (k < nk) {
      kv = ((u64)(~f32_sortable(ksc[k])) << 32) | ((u64)(u32)c << 16) | (u32)k;
      obx = kbox[k];
    } else {
      kv = ((u64)(~f32_sortable(-1e9f)) << 32) | ((u64)(u32)c << 16) | (u32)k;
      obx = make_float4(0.f, 0.f, 0.f, 0.f);
    }
    cand_key[bc * KK + k] = kv;
    cand_box[bc * KK + k] = obx;
  }
}

__device__ __forceinline__ void sort128(u64* smallkeys, int tid) {
  u64 v = (tid < 128) ? smallkeys[tid] : ~0ull;
  const u32 t = (u32)tid;
  for (u32 kk = 2; kk <= 128; kk <<= 1) {
    for (u32 j = kk >> 1; j > 0; j >>= 1) {
      if (j >= 64) {
        if (tid < 128) smallkeys[t] = v;
        __syncthreads();
        u64 p = (tid < 128) ? smallkeys[t ^ j] : ~0ull;
        __syncthreads();
        if (tid < 128) {
          bool up = ((t & kk) == 0);
          bool lower = ((t & j) == 0);
          bool takemin = (up == lower);
          bool pless = (p < v);
          v = (takemin == pless) ? p : v;
        }
      } else if (tid < 128) {
        u64 p = __shfl_xor(v, (int)j);
        bool up = ((t & kk) == 0);
        bool lower = ((t & j) == 0);
        bool takemin = (up == lower);
        bool pless = (p < v);
        v = (takemin == pless) ? p : v;
      }
    }
  }
  if (tid < 128) smallkeys[t] = v;
  __syncthreads();
}

// Kernel 3: one block per image. Radix-select rank-99 key T over 8000 unique
// keys; break to a 128-sort once <=128 candidates remain; gather the
// exactly-100 keys <= T, sort, write [K,6].
__global__ __launch_bounds__(1024) void topk_select(
    const u64* __restrict__ cand_key,    // [B, C*K]
    const float4* __restrict__ cand_box, // [B*C, K]
    float* __restrict__ out)             // [B, K, 6]
{
  const int b = blockIdx.x;
  const int tid = threadIdx.x;
  const int lane = tid & 63, wv = tid >> 6;
  const int N = CC * KK;                 // 8000
  const u64* __restrict__ keys_g = cand_key + (size_t)b * N;

  __shared__ u16 candA[CC * KK];         // 16 KB
  __shared__ u16 candB[CC * KK];         // 16 KB
  __shared__ u32 whist[16][256];         // 16 KB
  __shared__ u32 bins[256];
  __shared__ u64 smallkeys[128];
  __shared__ int ncand_s, rank_s, q_s;
  __shared__ u32 cnt_s;

  if (tid == 0) { ncand_s = N; rank_s = KK - 1; }

  u16* cur = candA;
  u16* oth = candB;
  bool first = true;
  int d = 7;
  for (;;) {
    for (int t = tid; t < 16 * 256; t += 1024) ((u32*)whist)[t] = 0;
    __syncthreads();
    const int nc = first ? N : ncand_s;
    const int sh = d * 8;
    for (int t0 = 0; t0 < nc; t0 += 1024) {
      const int t = t0 + tid;
      if (t < nc) {
        const int idx = first ? t : (int)cur[t];
        u32 dig = (u32)((keys_g[idx] >> sh) & 0xFF);
        atomicAdd(&whist[wv][dig], 1u);
      }
    }
    __syncthreads();
    if (tid < 256) {
      u32 s = 0;
      #pragma unroll
      for (int w = 0; w < 16; ++w) s += whist[w][tid];
      bins[tid] = s;
    }
    __syncthreads();
    if (wv == 0) {
      u32 c0 = bins[lane * 4 + 0], c1 = bins[lane * 4 + 1];
      u32 c2 = bins[lane * 4 + 2], c3 = bins[lane * 4 + 3];
      u32 lsum = c0 + c1 + c2 + c3;
      u32 incl = lsum;
      #pragma unroll
      for (int off = 1; off < 64; off <<= 1) {
        u32 v = __shfl_up(incl, off);
        if (lane >= off) incl += v;
      }
      u32 excl = incl - lsum;
      int rk = rank_s;
      u32 s0 = excl, s1 = excl + c0, s2 = s1 + c1, s3 = s2 + c2;
      int q = -1; u32 nr = 0;
      if (rk >= (int)s0 && rk < (int)(s0 + c0)) { q = lane * 4 + 0; nr = rk - s0; }
      else if (rk >= (int)s1 && rk < (int)(s1 + c1)) { q = lane * 4 + 1; nr = rk - s1; }
      else if (rk >= (int)s2 && rk < (int)(s2 + c2)) { q = lane * 4 + 2; nr = rk - s2; }
      else if (rk >= (int)s3 && rk < (int)(s3 + c3)) { q = lane * 4 + 3; nr = rk - s3; }
      if (q >= 0) { q_s = q; rank_s = (int)nr; }
    }
    if (tid == 0) cnt_s = 0;
    __syncthreads();
    const int q = q_s;
    for (int t0 = 0; t0 < nc; t0 += 1024) {
      const int t = t0 + tid;
      int idx = 0; bool m = false;
      if (t < nc) {
        idx = first ? t : (int)cur[t];
        m = ((int)((keys_g[idx] >> sh) & 0xFF) == q);
      }
      u64 bal = __ballot(m);
      u32 base = 0;
      if (lane == 0 && bal) base = atomicAdd(&cnt_s, (u32)__popcll(bal));
      base = __shfl(base, 0);
      if (m) oth[base + (u32)__popcll(bal & ((1ull << lane) - 1ull))] = (u16)idx;
    }
    __syncthreads();
    if (tid == 0) ncand_s = (int)cnt_s;
    { u16* tmp = cur; cur = oth; oth = tmp; }
    first = false;
    __syncthreads();
    if (ncand_s <= 128 || d == 0) break;
    --d;
  }

  u64 T;
  const int nc2 = ncand_s;
  if (nc2 == 1) {
    T = keys_g[cur[0]];
  } else {
    if (tid < 128) smallkeys[tid] = (tid < nc2) ? keys_g[cur[tid]] : ~0ull;
    __syncthreads();
    sort128(smallkeys, tid);
    T = smallkeys[rank_s];                 // rank within candidate set
    __syncthreads();
  }

  // gather the exactly-100 keys <= T (wave-aggregated)
  if (tid == 0) cnt_s = 0;
  if (tid < 128) smallkeys[tid] = ~0ull;
  __syncthreads();
  for (int t0 = 0; t0 < N; t0 += 1024) {
    const int t = t0 + tid;
    u64 k = 0; bool m = false;
    if (t < N) { k = keys_g[t]; m = (k <= T); }
    u64 bal = __ballot(m);
    u32 base = 0;
    if (lane == 0 && bal) base = atomicAdd(&cnt_s, (u32)__popcll(bal));
    base = __shfl(base, 0);
    if (m) {
      u32 p = base + (u32)__popcll(bal & ((1ull << lane) - 1ull));
      if (p < 128) smallkeys[p] = k;
    }
  }
  __syncthreads();

  sort128(smallkeys, tid);

  if (tid < KK) {
    const u64 kv = smallkeys[tid];
    const float s = sortable_to_f32(~(u32)(kv >> 32));
    float x1 = 0.f, y1 = 0.f, x2 = 0.f, y2 = 0.f, so = 0.f, cf = -1.0f;
    if (s > -5.0e8f) {                     // valid = top_s > NEG*0.5
      int c = (int)((kv >> 16) & 0xFFFFull);
      int k = (int)(kv & 0xFFFFull);
      float4 bx = cand_box[((size_t)b * CC + c) * KK + k];
      x1 = bx.x; y1 = bx.y; x2 = bx.z; y2 = bx.w;
      so = s; cf = (float)c;
    }
    float* o = out + ((size_t)b * KK + tid) * 6;
    o[0] = x1; o[1] = y1; o[2] = x2; o[3] = y2; o[4] = so; o[5] = cf;
  }
}

extern "C" void kernel_launch(void* const* d_in, const int* in_sizes, int n_in,
                              void* d_out, int out_size, void* d_ws, size_t ws_size,
                              hipStream_t stream) {
  (void)in_sizes; (void)n_in; (void)out_size; (void)ws_size;
  const float* rois   = (const float*)d_in[0];
  const float* scores = (const float*)d_in[1];
  const float* deltas = (const float*)d_in[2];
  const int*   im_hw  = (const int*)d_in[3];

  char* ws = (char*)d_ws;
  float4* box_g    = (float4*)ws;                  // 320*512*16 = 2,621,440
  float*  sco_g    = (float*)(ws + 2621440);       // 320*512*4  =   655,360
  u64*    cand_key = (u64*)(ws + 3276800);         // 4*80*100*8 =   256,000
  float4* cand_box = (float4*)(ws + 3532800);      // 4*80*100*16=   512,000

  sort_decode<<<BB * CC, 512, 0, stream>>>(rois, scores, deltas, im_hw,
                                           box_g, sco_g);
  nms_lazy<<<BB * CC, 64, 0, stream>>>(box_g, sco_g, cand_key, cand_box);
  topk_select<<<BB, 1024, 0, stream>>>(cand_key, cand_box, (float*)d_out);
}

// Round 8
// 63.280 us; speedup vs baseline: 1.5667x; 1.4523x over previous
//
#include <hip/hip_runtime.h>
#include <cstdint>

#define BB 4
#define RR 512
#define CC 80
#define KK 100
#define NMS_TH 0.3f
#define SCORE_TH 0.1f
#define DWH_CLIP 4.135166556742356f

typedef unsigned short u16;
typedef unsigned int u32;
typedef unsigned long long u64;

__device__ __forceinline__ u32 f32_sortable(float f) {
  u32 u = __float_as_uint(f);
  u32 mask = (u32)((int)u >> 31) | 0x80000000u;
  return u ^ mask;
}
__device__ __forceinline__ float sortable_to_f32(u32 s) {
  u32 u = (s & 0x80000000u) ? (s ^ 0x80000000u) : ~s;
  return __uint_as_float(u);
}

// Kernel 1: one block of 512 per (b,c). Fused: score-sort, decode, lazy
// greedy NMS with wave-parallel suppression + precomputed in-chunk row
// masks, emit first <=100 kept candidates. Certain-test (validated R4-R7):
// q > TH <=> inter*(1+TH)/TH > ai+aj+1e-9 in reals; band +-2e-6 >> total
// rounding error ~3e-7; exact IEEE-divide fallback for band cases.
__global__ __launch_bounds__(512) void nms_fused(
    const float* __restrict__ rois,     // [B,R,4]
    const float* __restrict__ scores,   // [B*R, C+1]
    const float* __restrict__ deltas,   // [B*R, (C+1)*4]
    const int*   __restrict__ im_hw,    // [B,2]
    u64*   __restrict__ cand_key,       // [B*C, K]
    float4* __restrict__ cand_box)      // [B*C, K]
{
#pragma clang fp contract(off)
  const int bc = blockIdx.x;
  const int b = bc / CC, c = bc % CC;
  const int tid = threadIdx.x;
  const int lane = tid & 63, wv = tid >> 6;

  __shared__ u64    keyarr[RR];        // 4 KB (sort)
  __shared__ float4 box_s[RR];         // 8 KB sorted boxes
  __shared__ float  sco_s[RR];         // 2 KB sorted scores
  __shared__ u64    rmk[64];           // per-row suppressed-col bits (chunk)
  __shared__ u64    supacc;            // candidates suppressed by prior kept
  __shared__ float4 kbox[KK];
  __shared__ float  ksc[KK];
  __shared__ float  karea[KK];
  __shared__ int    nkept_s;

  const float fh = (float)im_hw[b * 2 + 0] - 1.0f;
  const float fw = (float)im_hw[b * 2 + 1] - 1.0f;

  // ---- hybrid bitonic sort: shfl for j<64, LDS for j>=64 ----
  {
    const float sc = scores[(b * RR + tid) * (CC + 1) + (c + 1)];
    u64 v = ((u64)(~f32_sortable(sc)) << 32) | (u32)tid;  // score desc, idx asc
    const u32 t = (u32)tid;
    for (u32 kk = 2; kk <= RR; kk <<= 1) {
      for (u32 j = kk >> 1; j > 0; j >>= 1) {
        u64 p;
        if (j >= 64) {
          keyarr[t] = v;
          __syncthreads();
          p = keyarr[t ^ j];
          __syncthreads();
        } else {
          p = __shfl_xor(v, (int)j);
        }
        bool up = ((t & kk) == 0);
        bool lower = ((t & j) == 0);
        bool takemin = (up == lower);
        bool pless = (p < v);
        v = (takemin == pless) ? p : v;
      }
    }
    keyarr[t] = v;
  }
  __syncthreads();

  // ---- decode into sorted order ----
  {
    const u64 kv = keyarr[tid];
    const int r = (int)(kv & 0xFFFFFFFFull);
    const float sc = sortable_to_f32(~(u32)(kv >> 32));   // bit-exact original
    const float4 roi = *(const float4*)&rois[(b * RR + r) * 4];
    const int base = (b * RR + r) * (CC + 1) + (c + 1);
    const float4 d = *(const float4*)&deltas[base * 4];

    float w  = roi.z - roi.x;
    float h  = roi.w - roi.y;
    float cx = roi.x + 0.5f * w;
    float cy = roi.y + 0.5f * h;
    float dw = fminf(d.z, DWH_CLIP);
    float dh = fminf(d.w, DWH_CLIP);
    float pcx = d.x * w + cx;
    float pcy = d.y * h + cy;
    float pw = w * expf(dw);
    float ph = h * expf(dh);
    float hx = 0.5f * pw, hy = 0.5f * ph;
    float x1 = fminf(fmaxf(pcx - hx, 0.0f), fw);
    float y1 = fminf(fmaxf(pcy - hy, 0.0f), fh);
    float x2 = fminf(fmaxf(pcx + hx, 0.0f), fw);
    float y2 = fminf(fmaxf(pcy + hy, 0.0f), fh);

    box_s[tid] = make_float4(x1, y1, x2, y2);
    sco_s[tid] = sc;
    if (tid == 0) nkept_s = 0;
  }
  __syncthreads();

  // ---- lazy greedy NMS over 8 chunks of 64 ----
  int nk = 0;
  for (int w = 0; w < 8; ++w) {
    // every wave holds the SAME 64 candidates (lane-indexed)
    const float4 bx = box_s[w * 64 + lane];
    const float  sc = sco_s[w * 64 + lane];
    const float  ar = (bx.z - bx.x) * (bx.w - bx.y);
    const float  areps = ar + 1e-9f;

    if (tid < 64) rmk[tid] = 0ull;
    if (tid == 64) supacc = 0ull;
    __syncthreads();

    // (a) within-chunk row masks: wave wv covers columns wv*8..wv*8+7
    {
      u64 myrow = 0;
      #pragma unroll
      for (int jj = 0; jj < 8; ++jj) {
        const int j = wv * 8 + jj;
        const float4 cb = box_s[w * 64 + j];          // broadcast
        const float ca = (cb.z - cb.x) * (cb.w - cb.y);
        float iw = fminf(bx.z, cb.z) - fmaxf(bx.x, cb.x);
        float ih = fminf(bx.w, cb.w) - fmaxf(bx.y, cb.y);
        iw = fmaxf(iw, 0.0f);
        ih = fmaxf(ih, 0.0f);
        const float inter = iw * ih;
        const float S = ca + areps;
        bool yes = inter * 4.3333247f > S;            // 13/3*(1-2e-6)
        const bool no = inter * 4.3333420f < S;       // 13/3*(1+2e-6)
        if (__any(!(yes || no))) {                    // ~never taken
          const float denom = ((ca + ar) - inter) + 1e-9f;  // exact ref order
          const bool pe = inter / denom > NMS_TH;
          yes = (yes || no) ? yes : pe;
        }
        myrow |= yes ? (1ull << j) : 0ull;
      }
      myrow &= ~((2ull << lane) - 1ull);              // only cols > row (lane=63 -> 0)
      if (myrow) atomicOr(&rmk[lane], myrow);
    }

    // (b) suppression by previously-kept boxes, wave-strided slices
    {
      bool sup = false;
      for (int k = wv; k < nk; k += 8) {
        const float4 kb = kbox[k];                    // broadcast
        const float  ka = karea[k];
        float iw = fminf(bx.z, kb.z) - fmaxf(bx.x, kb.x);
        float ih = fminf(bx.w, kb.w) - fmaxf(bx.y, kb.y);
        iw = fmaxf(iw, 0.0f);
        ih = fmaxf(ih, 0.0f);
        const float inter = iw * ih;
        const float S = ka + areps;
        bool yes = inter * 4.3333247f > S;
        const bool no = inter * 4.3333420f < S;
        if (__any(!(yes || no))) {                    // ~never taken
          const float denom = ((ka + ar) - inter) + 1e-9f;
          const bool pe = inter / denom > NMS_TH;
          yes = (yes || no) ? yes : pe;
        }
        sup = sup || yes;
      }
      const u64 bal = __ballot(sup);
      if (lane == 0 && bal) atomicOr(&supacc, bal);
    }
    __syncthreads();

    // (c) serial scan (wave 0): no IoU, no ballot in the chain
    if (wv == 0) {
      u64 todo = __ballot(sc > SCORE_TH) & ~supacc;
      int nkl = nk;
      while (todo) {
        const int i = __ffsll((long long)todo) - 1;   // highest remaining score
        if (lane == 0) {
          const float4 kb = box_s[w * 64 + i];
          kbox[nkl] = kb;
          ksc[nkl] = sco_s[w * 64 + i];
          karea[nkl] = (kb.z - kb.x) * (kb.w - kb.y);
        }
        ++nkl;
        if (nkl >= KK) break;
        const u64 ri = rmk[i];                        // broadcast ds_read
        todo &= ~((2ull << i) - 1ull);                // clear bits <= i
        todo &= ~ri;
      }
      if (lane == 0) nkept_s = nkl;
    }
    __syncthreads();
    nk = nkept_s;
    if (nk >= KK) break;
  }

  // ---- emit (pads unique, score = -1e9 = reference NEG) ----
  if (tid < KK) {
    const int k = tid;
    u64 kv; float4 obx;
    if (k < nk) {
      kv = ((u64)(~f32_sortable(ksc[k])) << 32) | ((u64)(u32)c << 16) | (u32)k;
      obx = kbox[k];
    } else {
      kv = ((u64)(~f32_sortable(-1e9f)) << 32) | ((u64)(u32)c << 16) | (u32)k;
      obx = make_float4(0.f, 0.f, 0.f, 0.f);
    }
    cand_key[bc * KK + k] = kv;
    cand_box[bc * KK + k] = obx;
  }
}

__device__ __forceinline__ void sort128(u64* smallkeys, int tid) {
  u64 v = (tid < 128) ? smallkeys[tid] : ~0ull;
  const u32 t = (u32)tid;
  for (u32 kk = 2; kk <= 128; kk <<= 1) {
    for (u32 j = kk >> 1; j > 0; j >>= 1) {
      if (j >= 64) {
        if (tid < 128) smallkeys[t] = v;
        __syncthreads();
        u64 p = (tid < 128) ? smallkeys[t ^ j] : ~0ull;
        __syncthreads();
        if (tid < 128) {
          bool up = ((t & kk) == 0);
          bool lower = ((t & j) == 0);
          bool takemin = (up == lower);
          bool pless = (p < v);
          v = (takemin == pless) ? p : v;
        }
      } else if (tid < 128) {
        u64 p = __shfl_xor(v, (int)j);
        bool up = ((t & kk) == 0);
        bool lower = ((t & j) == 0);
        bool takemin = (up == lower);
        bool pless = (p < v);
        v = (takemin == pless) ? p : v;
      }
    }
  }
  if (tid < 128) smallkeys[t] = v;
  __syncthreads();
}

// Kernel 2: one block per image. Radix-select rank-99 key T over 8000 unique
// keys; break to a 128-sort once <=128 candidates remain; gather the
// exactly-100 keys <= T, sort, write [K,6].
__global__ __launch_bounds__(1024) void topk_select(
    const u64* __restrict__ cand_key,    // [B, C*K]
    const float4* __restrict__ cand_box, // [B*C, K]
    float* __restrict__ out)             // [B, K, 6]
{
  const int b = blockIdx.x;
  const int tid = threadIdx.x;
  const int lane = tid & 63, wv = tid >> 6;
  const int N = CC * KK;                 // 8000
  const u64* __restrict__ keys_g = cand_key + (size_t)b * N;

  __shared__ u16 candA[CC * KK];         // 16 KB
  __shared__ u16 candB[CC * KK];         // 16 KB
  __shared__ u32 whist[16][256];         // 16 KB
  __shared__ u32 bins[256];
  __shared__ u64 smallkeys[128];
  __shared__ int ncand_s, rank_s, q_s;
  __shared__ u32 cnt_s;

  if (tid == 0) { ncand_s = N; rank_s = KK - 1; }

  u16* cur = candA;
  u16* oth = candB;
  bool first = true;
  int d = 7;
  for (;;) {
    for (int t = tid; t < 16 * 256; t += 1024) ((u32*)whist)[t] = 0;
    __syncthreads();
    const int nc = first ? N : ncand_s;
    const int sh = d * 8;
    for (int t0 = 0; t0 < nc; t0 += 1024) {
      const int t = t0 + tid;
      if (t < nc) {
        const int idx = first ? t : (int)cur[t];
        u32 dig = (u32)((keys_g[idx] >> sh) & 0xFF);
        atomicAdd(&whist[wv][dig], 1u);
      }
    }
    __syncthreads();
    if (tid < 256) {
      u32 s = 0;
      #pragma unroll
      for (int w = 0; w < 16; ++w) s += whist[w][tid];
      bins[tid] = s;
    }
    __syncthreads();
    if (wv == 0) {
      u32 c0 = bins[lane * 4 + 0], c1 = bins[lane * 4 + 1];
      u32 c2 = bins[lane * 4 + 2], c3 = bins[lane * 4 + 3];
      u32 lsum = c0 + c1 + c2 + c3;
      u32 incl = lsum;
      #pragma unroll
      for (int off = 1; off < 64; off <<= 1) {
        u32 v = __shfl_up(incl, off);
        if (lane >= off) incl += v;
      }
      u32 excl = incl - lsum;
      int rk = rank_s;
      u32 s0 = excl, s1 = excl + c0, s2 = s1 + c1, s3 = s2 + c2;
      int q = -1; u32 nr = 0;
      if (rk >= (int)s0 && rk < (int)(s0 + c0)) { q = lane * 4 + 0; nr = rk - s0; }
      else if (rk >= (int)s1 && rk < (int)(s1 + c1)) { q = lane * 4 + 1; nr = rk - s1; }
      else if (rk >= (int)s2 && rk < (int)(s2 + c2)) { q = lane * 4 + 2; nr = rk - s2; }
      else if (rk >= (int)s3 && rk < (int)(s3 + c3)) { q = lane * 4 + 3; nr = rk - s3; }
      if (q >= 0) { q_s = q; rank_s = (int)nr; }
    }
    if (tid == 0) cnt_s = 0;
    __syncthreads();
    const int q = q_s;
    for (int t0 = 0; t0 < nc; t0 += 1024) {
      const int t = t0 + tid;
      int idx = 0; bool m = false;
      if (t < nc) {
        idx = first ? t : (int)cur[t];
        m = ((int)((keys_g[idx] >> sh) & 0xFF) == q);
      }
      u64 bal = __ballot(m);
      u32 base = 0;
      if (lane == 0 && bal) base = atomicAdd(&cnt_s, (u32)__popcll(bal));
      base = __shfl(base, 0);
      if (m) oth[base + (u32)__popcll(bal & ((1ull << lane) - 1ull))] = (u16)idx;
    }
    __syncthreads();
    if (tid == 0) ncand_s = (int)cnt_s;
    { u16* tmp = cur; cur = oth; oth = tmp; }
    first = false;
    __syncthreads();
    if (ncand_s <= 128 || d == 0) break;
    --d;
  }

  u64 T;
  const int nc2 = ncand_s;
  if (nc2 == 1) {
    T = keys_g[cur[0]];
  } else {
    if (tid < 128) smallkeys[tid] = (tid < nc2) ? keys_g[cur[tid]] : ~0ull;
    __syncthreads();
    sort128(smallkeys, tid);
    T = smallkeys[rank_s];                 // rank within candidate set
    __syncthreads();
  }

  // gather the exactly-100 keys <= T (wave-aggregated)
  if (tid == 0) cnt_s = 0;
  if (tid < 128) smallkeys[tid] = ~0ull;
  __syncthreads();
  for (int t0 = 0; t0 < N; t0 += 1024) {
    const int t = t0 + tid;
    u64 k = 0; bool m = false;
    if (t < N) { k = keys_g[t]; m = (k <= T); }
    u64 bal = __ballot(m);
    u32 base = 0;
    if (lane == 0 && bal) base = atomicAdd(&cnt_s, (u32)__popcll(bal));
    base = __shfl(base, 0);
    if (m) {
      u32 p = base + (u32)__popcll(bal & ((1ull << lane) - 1ull));
      if (p < 128) smallkeys[p] = k;
    }
  }
  __syncthreads();

  sort128(smallkeys, tid);

  if (tid < KK) {
    const u64 kv = smallkeys[tid];
    const float s = sortable_to_f32(~(u32)(kv >> 32));
    float x1 = 0.f, y1 = 0.f, x2 = 0.f, y2 = 0.f, so = 0.f, cf = -1.0f;
    if (s > -5.0e8f) {                     // valid = top_s > NEG*0.5
      int c = (int)((kv >> 16) & 0xFFFFull);
      int k = (int)(kv & 0xFFFFull);
      float4 bx = cand_box[((size_t)b * CC + c) * KK + k];
      x1 = bx.x; y1 = bx.y; x2 = bx.z; y2 = bx.w;
      so = s; cf = (float)c;
    }
    float* o = out + ((size_t)b * KK + tid) * 6;
    o[0] = x1; o[1] = y1; o[2] = x2; o[3] = y2; o[4] = so; o[5] = cf;
  }
}

extern "C" void kernel_launch(void* const* d_in, const int* in_sizes, int n_in,
                              void* d_out, int out_size, void* d_ws, size_t ws_size,
                              hipStream_t stream) {
  (void)in_sizes; (void)n_in; (void)out_size; (void)ws_size;
  const float* rois   = (const float*)d_in[0];
  const float* scores = (const float*)d_in[1];
  const float* deltas = (const float*)d_in[2];
  const int*   im_hw  = (const int*)d_in[3];

  char* ws = (char*)d_ws;
  u64*    cand_key = (u64*)ws;                     // 4*80*100*8 = 256,000
  float4* cand_box = (float4*)(ws + 256000);       // 4*80*100*16= 512,000

  nms_fused<<<BB * CC, 512, 0, stream>>>(rois, scores, deltas, im_hw,
                                         cand_key, cand_box);
  topk_select<<<BB, 1024, 0, stream>>>(cand_key, cand_box, (float*)d_out);
}